// Round 1
// baseline (347.762 us; speedup 1.0000x reference)
//
#include <hip/hip_runtime.h>
#include <hip/hip_bf16.h>
#include <cstdint>

#define N_TOK 4096
#define KTOP  64
#define DIM   1024
#define NLAT  16384

typedef __bf16 bf16x8 __attribute__((ext_vector_type(8)));
typedef float  floatx4 __attribute__((ext_vector_type(4)));

__device__ inline unsigned short f2bf(float f){
  unsigned int u = __float_as_uint(f);
  unsigned int r = (u + 0x7fffu + ((u >> 16) & 1u)) >> 16;  // RNE
  return (unsigned short)r;
}

__global__ __launch_bounds__(256) void cvt_bf16_kernel(
    const float* __restrict__ in, unsigned short* __restrict__ out, int n4){
  int i = blockIdx.x * blockDim.x + threadIdx.x;
  if (i >= n4) return;
  float4 v = ((const float4*)in)[i];
  ushort4 o;
  o.x = f2bf(v.x); o.y = f2bf(v.y); o.z = f2bf(v.z); o.w = f2bf(v.w);
  ((ushort4*)out)[i] = o;
}

// C[n,d] = sum_j x[n,j] * W_skip[d,j]  + b_dec[d]   (both operands row-major along j)
__global__ __launch_bounds__(256) void skip_gemm(
    const unsigned short* __restrict__ xb,   // [N_TOK][DIM] bf16
    const unsigned short* __restrict__ wb,   // [DIM][DIM]  bf16 (W_skip)
    const float* __restrict__ b_dec,
    float* __restrict__ out){
  __shared__ unsigned short As[64][40];   // +8 pad: row stride 80B (16B-aligned, 2-way bank alias = free)
  __shared__ unsigned short Bs[64][40];
  const int row0 = blockIdx.x * 64;
  const int col0 = blockIdx.y * 64;
  const int t    = threadIdx.x;
  const int lane = t & 63;
  const int w    = t >> 6;
  const int wr   = (w >> 1) * 32;
  const int wc   = (w & 1) * 32;
  const int lm   = lane & 15;
  const int kq   = lane >> 4;

  const int lr   = t >> 2;          // tile row 0..63 for staging
  const int lseg = (t & 3) * 8;     // ushort offset within 32-wide K slab

  floatx4 acc[2][2] = {};

  for (int k0 = 0; k0 < DIM; k0 += 32){
    *(uint4*)(&As[lr][lseg]) = *(const uint4*)(xb + (size_t)(row0 + lr) * DIM + k0 + lseg);
    *(uint4*)(&Bs[lr][lseg]) = *(const uint4*)(wb + (size_t)(col0 + lr) * DIM + k0 + lseg);
    __syncthreads();
    bf16x8 a0 = *(const bf16x8*)(&As[wr      + lm][kq * 8]);
    bf16x8 a1 = *(const bf16x8*)(&As[wr + 16 + lm][kq * 8]);
    bf16x8 b0 = *(const bf16x8*)(&Bs[wc      + lm][kq * 8]);
    bf16x8 b1 = *(const bf16x8*)(&Bs[wc + 16 + lm][kq * 8]);
    acc[0][0] = __builtin_amdgcn_mfma_f32_16x16x32_bf16(a0, b0, acc[0][0], 0, 0, 0);
    acc[0][1] = __builtin_amdgcn_mfma_f32_16x16x32_bf16(a0, b1, acc[0][1], 0, 0, 0);
    acc[1][0] = __builtin_amdgcn_mfma_f32_16x16x32_bf16(a1, b0, acc[1][0], 0, 0, 0);
    acc[1][1] = __builtin_amdgcn_mfma_f32_16x16x32_bf16(a1, b1, acc[1][1], 0, 0, 0);
    __syncthreads();
  }

  // C/D layout: col = lane&15, row = (lane>>4)*4 + reg
  const int rq = (lane >> 4) * 4;
  for (int mi = 0; mi < 2; mi++){
    for (int ni = 0; ni < 2; ni++){
      int col = col0 + wc + ni * 16 + lm;
      float bd = b_dec[col];
      for (int r = 0; r < 4; r++){
        int row = row0 + wr + mi * 16 + rq + r;
        out[(size_t)row * DIM + col] = acc[mi][ni][r] + bd;
      }
    }
  }
}

// Per-token: out_row += sum_k act_k * W_dec[idx_k,:]; e = y - out; atomic sum(e^2)
__global__ __launch_bounds__(256) void decode_residual(
    const float* __restrict__ y,
    const float* __restrict__ la,
    const int*   __restrict__ li,
    const float* __restrict__ Wd,
    const float* __restrict__ pe,
    const float* __restrict__ pes,
    float* __restrict__ out,
    float* __restrict__ sse){
  const int n = blockIdx.x;
  const int t = threadIdx.x;
  __shared__ float s_act[KTOP];
  __shared__ int   s_idx[KTOP];
  __shared__ float s_red[4];
  if (t < KTOP){
    int id = li[n * KTOP + t];
    s_idx[t] = id;
    s_act[t] = (la[n * KTOP + t] + pe[id]) * pes[id];
  }
  __syncthreads();
  float4 acc = ((const float4*)(out + (size_t)n * DIM))[t];
  #pragma unroll 8
  for (int k = 0; k < KTOP; k++){
    const float a = s_act[k];
    const float4 wv = ((const float4*)(Wd + (size_t)s_idx[k] * DIM))[t];
    acc.x += a * wv.x; acc.y += a * wv.y; acc.z += a * wv.z; acc.w += a * wv.w;
  }
  ((float4*)(out + (size_t)n * DIM))[t] = acc;
  float4 yv = ((const float4*)(y + (size_t)n * DIM))[t];
  float ex = yv.x - acc.x, ey = yv.y - acc.y, ez = yv.z - acc.z, ew = yv.w - acc.w;
  float s = ex*ex + ey*ey + ez*ez + ew*ew;
  #pragma unroll
  for (int off = 32; off > 0; off >>= 1) s += __shfl_down(s, off, 64);
  if ((t & 63) == 0) s_red[t >> 6] = s;
  __syncthreads();
  if (t == 0) atomicAdd(sse, s_red[0] + s_red[1] + s_red[2] + s_red[3]);
}

// Per-column sums of y and global sum(y^2)
__global__ __launch_bounds__(256) void ystats(
    const float* __restrict__ y, float* __restrict__ colsum, float* __restrict__ sumsq){
  const int t  = threadIdx.x;
  const int r0 = blockIdx.x * 16;
  float4 cs = {0.f, 0.f, 0.f, 0.f};
  float sq = 0.f;
  for (int r = 0; r < 16; r++){
    float4 v = ((const float4*)(y + (size_t)(r0 + r) * DIM))[t];
    cs.x += v.x; cs.y += v.y; cs.z += v.z; cs.w += v.w;
    sq += v.x*v.x + v.y*v.y + v.z*v.z + v.w*v.w;
  }
  atomicAdd(&colsum[t*4+0], cs.x);
  atomicAdd(&colsum[t*4+1], cs.y);
  atomicAdd(&colsum[t*4+2], cs.z);
  atomicAdd(&colsum[t*4+3], cs.w);
  #pragma unroll
  for (int off = 32; off > 0; off >>= 1) sq += __shfl_down(sq, off, 64);
  __shared__ float s_red[4];
  if ((t & 63) == 0) s_red[t >> 6] = sq;
  __syncthreads();
  if (t == 0) atomicAdd(sumsq, s_red[0] + s_red[1] + s_red[2] + s_red[3]);
}

// ws[0]=sse, ws[1]=sumsq, ws[4..1028)=colsum
__global__ __launch_bounds__(256) void fvu_kernel(
    const float* __restrict__ ws, float* __restrict__ fvu_out){
  const int t = threadIdx.x;
  float4 c = ((const float4*)(ws + 4))[t];
  float s = c.x*c.x + c.y*c.y + c.z*c.z + c.w*c.w;
  #pragma unroll
  for (int off = 32; off > 0; off >>= 1) s += __shfl_down(s, off, 64);
  __shared__ float s_red[4];
  if ((t & 63) == 0) s_red[t >> 6] = s;
  __syncthreads();
  if (t == 0){
    float ss = s_red[0] + s_red[1] + s_red[2] + s_red[3];
    float tv = ws[1] - ss / (float)N_TOK;   // sum(y^2) - sum_d colsum_d^2 / N
    fvu_out[0] = ws[0] / tv;
  }
}

extern "C" void kernel_launch(void* const* d_in, const int* in_sizes, int n_in,
                              void* d_out, int out_size, void* d_ws, size_t ws_size,
                              hipStream_t stream){
  const float* x   = (const float*)d_in[0];
  const float* y   = (const float*)d_in[1];
  const float* la  = (const float*)d_in[2];
  const int*   li  = (const int*)d_in[3];
  const float* Wd  = (const float*)d_in[4];
  const float* bd  = (const float*)d_in[5];
  const float* pe  = (const float*)d_in[6];
  const float* pes = (const float*)d_in[7];
  const float* Wsk = (const float*)d_in[8];
  float* out = (float*)d_out;

  float* accs = (float*)d_ws;  // [0]=sse [1]=sumsq [4..1028)=colsum
  unsigned short* xb = (unsigned short*)((char*)d_ws + 8192);
  unsigned short* wb = (unsigned short*)((char*)d_ws + 8192 + (size_t)N_TOK * DIM * 2);

  hipMemsetAsync(d_ws, 0, 8192, stream);
  cvt_bf16_kernel<<<(N_TOK * DIM / 4 + 255) / 256, 256, 0, stream>>>(x,   xb, N_TOK * DIM / 4);
  cvt_bf16_kernel<<<(DIM * DIM / 4 + 255) / 256, 256, 0, stream>>>(Wsk, wb, DIM * DIM / 4);
  ystats<<<N_TOK / 16, 256, 0, stream>>>(y, accs + 4, accs + 1);
  skip_gemm<<<dim3(N_TOK / 64, DIM / 64), 256, 0, stream>>>(xb, wb, bd, out);
  decode_residual<<<N_TOK, 256, 0, stream>>>(y, la, li, Wd, pe, pes, out, accs);
  fvu_kernel<<<1, 256, 0, stream>>>(accs, out + (size_t)N_TOK * DIM);
}

// Round 2
// 269.717 us; speedup vs baseline: 1.2894x; 1.2894x over previous
//
#include <hip/hip_runtime.h>
#include <hip/hip_bf16.h>
#include <cstdint>

#define N_TOK 4096
#define KTOP  64
#define DIM   1024
#define NLAT  16384

typedef __bf16 bf16x8 __attribute__((ext_vector_type(8)));
typedef float  floatx4 __attribute__((ext_vector_type(4)));

#define GLOBAL_AS(p) ((const __attribute__((address_space(1))) void*)(p))
#define LDS_AS(p)    ((__attribute__((address_space(3))) void*)(p))

__device__ inline unsigned short f2bf(float f){
  unsigned int u = __float_as_uint(f);
  unsigned int r = (u + 0x7fffu + ((u >> 16) & 1u)) >> 16;  // RNE
  return (unsigned short)r;
}
__device__ inline float bflo(unsigned int u){ return __uint_as_float(u << 16); }
__device__ inline float bfhi(unsigned int u){ return __uint_as_float(u & 0xffff0000u); }

__global__ __launch_bounds__(256) void cvt_bf16_kernel(
    const float* __restrict__ in, unsigned short* __restrict__ out, int n4){
  int i = blockIdx.x * blockDim.x + threadIdx.x;
  if (i >= n4) return;
  float4 v = ((const float4*)in)[i];
  ushort4 o;
  o.x = f2bf(v.x); o.y = f2bf(v.y); o.z = f2bf(v.z); o.w = f2bf(v.w);
  ((ushort4*)out)[i] = o;
}

// C[n,d] = sum_j x[n,j]*W_skip[d,j] + b_dec[d].  128x128 tile, BK=32, m97-style.
__global__ __launch_bounds__(256) void skip_gemm(
    const unsigned short* __restrict__ xb,   // [N_TOK][DIM] bf16
    const unsigned short* __restrict__ wb,   // [DIM][DIM]  bf16
    const float* __restrict__ b_dec,
    float* __restrict__ out){
  __shared__ unsigned short As[128][32];   // 8 KB, unpadded (global_load_lds layout)
  __shared__ unsigned short Bs[128][32];
  const int row0 = blockIdx.x * 128;
  const int col0 = blockIdx.y * 128;
  const int t    = threadIdx.x;
  const int lane = t & 63;
  const int w    = t >> 6;
  const int wr   = (w >> 1) * 64;
  const int wc   = (w & 1) * 64;
  const int lm   = lane & 15;
  const int kq   = lane >> 4;

  const int sr   = t >> 2;         // staging row 0..63 (+64 on 2nd call)
  const int sc   = (t & 3) * 8;    // staging col (ushort)

  floatx4 acc[4][4] = {};

  for (int k0 = 0; k0 < DIM; k0 += 32){
    __builtin_amdgcn_global_load_lds(GLOBAL_AS(xb + (size_t)(row0 + sr) * DIM + k0 + sc),
                                     LDS_AS(&As[sr][sc]), 16, 0, 0);
    __builtin_amdgcn_global_load_lds(GLOBAL_AS(xb + (size_t)(row0 + 64 + sr) * DIM + k0 + sc),
                                     LDS_AS(&As[64 + sr][sc]), 16, 0, 0);
    __builtin_amdgcn_global_load_lds(GLOBAL_AS(wb + (size_t)(col0 + sr) * DIM + k0 + sc),
                                     LDS_AS(&Bs[sr][sc]), 16, 0, 0);
    __builtin_amdgcn_global_load_lds(GLOBAL_AS(wb + (size_t)(col0 + 64 + sr) * DIM + k0 + sc),
                                     LDS_AS(&Bs[64 + sr][sc]), 16, 0, 0);
    __syncthreads();
    bf16x8 af[4], bf[4];
    #pragma unroll
    for (int mi = 0; mi < 4; mi++) af[mi] = *(const bf16x8*)(&As[wr + mi * 16 + lm][kq * 8]);
    #pragma unroll
    for (int ni = 0; ni < 4; ni++) bf[ni] = *(const bf16x8*)(&Bs[wc + ni * 16 + lm][kq * 8]);
    #pragma unroll
    for (int mi = 0; mi < 4; mi++)
      #pragma unroll
      for (int ni = 0; ni < 4; ni++)
        acc[mi][ni] = __builtin_amdgcn_mfma_f32_16x16x32_bf16(af[mi], bf[ni], acc[mi][ni], 0, 0, 0);
    __syncthreads();
  }

  const int rq = (lane >> 4) * 4;   // C/D: col=lane&15, row=(lane>>4)*4+reg
  #pragma unroll
  for (int mi = 0; mi < 4; mi++){
    #pragma unroll
    for (int ni = 0; ni < 4; ni++){
      int col = col0 + wc + ni * 16 + lm;
      float bd = b_dec[col];
      #pragma unroll
      for (int r = 0; r < 4; r++){
        int row = row0 + wr + mi * 16 + rq + r;
        out[(size_t)row * DIM + col] = acc[mi][ni][r] + bd;
      }
    }
  }
}

// 2 tokens/block, 8 cols/thread. out += sum_k act_k * W_dec_bf16[idx_k]; sse += ||y-out||^2
__global__ __launch_bounds__(256) void decode_residual(
    const float* __restrict__ y,
    const float* __restrict__ la,
    const int*   __restrict__ li,
    const unsigned short* __restrict__ Wdb,   // [NLAT][DIM] bf16
    const float* __restrict__ pe,
    const float* __restrict__ pes,
    float* __restrict__ out,
    float* __restrict__ sse){
  const int n0 = blockIdx.x * 2;
  const int t  = threadIdx.x;
  const int half = t >> 7;          // which token
  const int lt   = t & 127;         // col group: cols 8*lt..8*lt+7
  const int n    = n0 + half;
  __shared__ float s_act[2][KTOP];
  __shared__ int   s_idx[2][KTOP];
  __shared__ float s_red[4];
  if (t < 128){
    int tok = t >> 6, k = t & 63;
    int id = li[(n0 + tok) * KTOP + k];
    s_idx[tok][k] = id;
    s_act[tok][k] = (la[(n0 + tok) * KTOP + k] + pe[id]) * pes[id];
  }
  __syncthreads();
  float* op = out + (size_t)n * DIM + lt * 8;
  float4 o0 = ((const float4*)op)[0], o1 = ((const float4*)op)[1];
  float acc[8] = {o0.x, o0.y, o0.z, o0.w, o1.x, o1.y, o1.z, o1.w};
  #pragma unroll 8
  for (int k = 0; k < KTOP; k++){
    const float a = s_act[half][k];
    const uint4 wv = *(const uint4*)(Wdb + (size_t)s_idx[half][k] * DIM + lt * 8);
    acc[0] += a * bflo(wv.x); acc[1] += a * bfhi(wv.x);
    acc[2] += a * bflo(wv.y); acc[3] += a * bfhi(wv.y);
    acc[4] += a * bflo(wv.z); acc[5] += a * bfhi(wv.z);
    acc[6] += a * bflo(wv.w); acc[7] += a * bfhi(wv.w);
  }
  ((float4*)op)[0] = make_float4(acc[0], acc[1], acc[2], acc[3]);
  ((float4*)op)[1] = make_float4(acc[4], acc[5], acc[6], acc[7]);
  const float* yp = y + (size_t)n * DIM + lt * 8;
  float4 y0 = ((const float4*)yp)[0], y1 = ((const float4*)yp)[1];
  float e0 = y0.x - acc[0], e1 = y0.y - acc[1], e2 = y0.z - acc[2], e3 = y0.w - acc[3];
  float e4 = y1.x - acc[4], e5 = y1.y - acc[5], e6 = y1.z - acc[6], e7 = y1.w - acc[7];
  float s = e0*e0 + e1*e1 + e2*e2 + e3*e3 + e4*e4 + e5*e5 + e6*e6 + e7*e7;
  #pragma unroll
  for (int off = 32; off > 0; off >>= 1) s += __shfl_down(s, off, 64);
  if ((t & 63) == 0) s_red[t >> 6] = s;
  __syncthreads();
  if (t == 0) atomicAdd(sse, s_red[0] + s_red[1] + s_red[2] + s_red[3]);
}

// Per-column sums of y and global sum(y^2); 128 blocks x 32 rows
__global__ __launch_bounds__(256) void ystats(
    const float* __restrict__ y, float* __restrict__ colsum, float* __restrict__ sumsq){
  const int t  = threadIdx.x;
  const int r0 = blockIdx.x * 32;
  float4 cs = {0.f, 0.f, 0.f, 0.f};
  float sq = 0.f;
  for (int r = 0; r < 32; r++){
    float4 v = ((const float4*)(y + (size_t)(r0 + r) * DIM))[t];
    cs.x += v.x; cs.y += v.y; cs.z += v.z; cs.w += v.w;
    sq += v.x*v.x + v.y*v.y + v.z*v.z + v.w*v.w;
  }
  atomicAdd(&colsum[t*4+0], cs.x);
  atomicAdd(&colsum[t*4+1], cs.y);
  atomicAdd(&colsum[t*4+2], cs.z);
  atomicAdd(&colsum[t*4+3], cs.w);
  #pragma unroll
  for (int off = 32; off > 0; off >>= 1) sq += __shfl_down(sq, off, 64);
  __shared__ float s_red[4];
  if ((t & 63) == 0) s_red[t >> 6] = sq;
  __syncthreads();
  if (t == 0) atomicAdd(sumsq, s_red[0] + s_red[1] + s_red[2] + s_red[3]);
}

// ws[0]=sse, ws[1]=sumsq, ws[4..1028)=colsum
__global__ __launch_bounds__(256) void fvu_kernel(
    const float* __restrict__ ws, float* __restrict__ fvu_out){
  const int t = threadIdx.x;
  float4 c = ((const float4*)(ws + 4))[t];
  float s = c.x*c.x + c.y*c.y + c.z*c.z + c.w*c.w;
  #pragma unroll
  for (int off = 32; off > 0; off >>= 1) s += __shfl_down(s, off, 64);
  __shared__ float s_red[4];
  if ((t & 63) == 0) s_red[t >> 6] = s;
  __syncthreads();
  if (t == 0){
    float ss = s_red[0] + s_red[1] + s_red[2] + s_red[3];
    float tv = ws[1] - ss / (float)N_TOK;
    fvu_out[0] = ws[0] / tv;
  }
}

extern "C" void kernel_launch(void* const* d_in, const int* in_sizes, int n_in,
                              void* d_out, int out_size, void* d_ws, size_t ws_size,
                              hipStream_t stream){
  const float* x   = (const float*)d_in[0];
  const float* y   = (const float*)d_in[1];
  const float* la  = (const float*)d_in[2];
  const int*   li  = (const int*)d_in[3];
  const float* Wd  = (const float*)d_in[4];
  const float* bd  = (const float*)d_in[5];
  const float* pe  = (const float*)d_in[6];
  const float* pes = (const float*)d_in[7];
  const float* Wsk = (const float*)d_in[8];
  float* out = (float*)d_out;

  float* accs = (float*)d_ws;  // [0]=sse [1]=sumsq [4..1028)=colsum
  unsigned short* xb  = (unsigned short*)((char*)d_ws + 8192);
  unsigned short* wb  = xb + (size_t)N_TOK * DIM;
  unsigned short* wdb = wb + (size_t)DIM * DIM;

  hipMemsetAsync(d_ws, 0, 8192, stream);
  cvt_bf16_kernel<<<N_TOK * DIM / 4 / 256, 256, 0, stream>>>(x,   xb,  N_TOK * DIM / 4);
  cvt_bf16_kernel<<<DIM * DIM / 4 / 256,   256, 0, stream>>>(Wsk, wb,  DIM * DIM / 4);
  cvt_bf16_kernel<<<NLAT * DIM / 4 / 256,  256, 0, stream>>>(Wd,  wdb, NLAT * DIM / 4);
  ystats<<<N_TOK / 32, 256, 0, stream>>>(y, accs + 4, accs + 1);
  skip_gemm<<<dim3(N_TOK / 128, DIM / 128), 256, 0, stream>>>(xb, wb, bd, out);
  decode_residual<<<N_TOK / 2, 256, 0, stream>>>(y, la, li, wdb, pe, pes, out, accs);
  fvu_kernel<<<1, 256, 0, stream>>>(accs, out + (size_t)N_TOK * DIM);
}

// Round 3
// 242.421 us; speedup vs baseline: 1.4345x; 1.1126x over previous
//
#include <hip/hip_runtime.h>
#include <hip/hip_bf16.h>
#include <cstdint>

#define N_TOK 4096
#define KTOP  64
#define DIM   1024
#define NLAT  16384
#define NCHUNK 8      // 128 cols/chunk -> 4 MB bf16 per chunk == one XCD L2

typedef __bf16 bf16x8 __attribute__((ext_vector_type(8)));
typedef float  floatx4 __attribute__((ext_vector_type(4)));

#define GLOBAL_AS(p) ((const __attribute__((address_space(1))) void*)(p))
#define LDS_AS(p)    ((__attribute__((address_space(3))) void*)(p))

__device__ inline unsigned short f2bf(float f){
  unsigned int u = __float_as_uint(f);
  unsigned int r = (u + 0x7fffu + ((u >> 16) & 1u)) >> 16;  // RNE
  return (unsigned short)r;
}
__device__ inline float bflo(unsigned int u){ return __uint_as_float(u << 16); }
__device__ inline float bfhi(unsigned int u){ return __uint_as_float(u & 0xffff0000u); }

__global__ __launch_bounds__(256) void cvt_bf16_kernel(
    const float* __restrict__ in, unsigned short* __restrict__ out, int n4){
  int i = blockIdx.x * blockDim.x + threadIdx.x;
  if (i >= n4) return;
  float4 v = ((const float4*)in)[i];
  ushort4 o;
  o.x = f2bf(v.x); o.y = f2bf(v.y); o.z = f2bf(v.z); o.w = f2bf(v.w);
  ((ushort4*)out)[i] = o;
}

// W_dec [NLAT][DIM] fp32 -> chunk-major bf16 [NCHUNK][NLAT][128]
__global__ __launch_bounds__(256) void cvt_wdec_chunked(
    const float* __restrict__ Wd, unsigned short* __restrict__ out){
  const int lat = blockIdx.x;
  const int t   = threadIdx.x;           // 4 cols per thread
  float4 v = ((const float4*)(Wd + (size_t)lat * DIM))[t];
  ushort4 o;
  o.x = f2bf(v.x); o.y = f2bf(v.y); o.z = f2bf(v.z); o.w = f2bf(v.w);
  const int chunk = t >> 5;              // (4t)/128
  const int off   = (t & 31) * 4;
  *(ushort4*)(out + ((size_t)chunk * NLAT + lat) * 128 + off) = o;
}

// C[n,d] = sum_j x[n,j]*W_skip[d,j] + b_dec[d].  128x128 tile, BK=32, m97-style.
__global__ __launch_bounds__(256) void skip_gemm(
    const unsigned short* __restrict__ xb,
    const unsigned short* __restrict__ wb,
    const float* __restrict__ b_dec,
    float* __restrict__ out){
  __shared__ unsigned short As[128][32];
  __shared__ unsigned short Bs[128][32];
  const int row0 = blockIdx.x * 128;
  const int col0 = blockIdx.y * 128;
  const int t    = threadIdx.x;
  const int lane = t & 63;
  const int w    = t >> 6;
  const int wr   = (w >> 1) * 64;
  const int wc   = (w & 1) * 64;
  const int lm   = lane & 15;
  const int kq   = lane >> 4;
  const int sr   = t >> 2;
  const int sc   = (t & 3) * 8;

  floatx4 acc[4][4] = {};

  for (int k0 = 0; k0 < DIM; k0 += 32){
    __builtin_amdgcn_global_load_lds(GLOBAL_AS(xb + (size_t)(row0 + sr) * DIM + k0 + sc),
                                     LDS_AS(&As[sr][sc]), 16, 0, 0);
    __builtin_amdgcn_global_load_lds(GLOBAL_AS(xb + (size_t)(row0 + 64 + sr) * DIM + k0 + sc),
                                     LDS_AS(&As[64 + sr][sc]), 16, 0, 0);
    __builtin_amdgcn_global_load_lds(GLOBAL_AS(wb + (size_t)(col0 + sr) * DIM + k0 + sc),
                                     LDS_AS(&Bs[sr][sc]), 16, 0, 0);
    __builtin_amdgcn_global_load_lds(GLOBAL_AS(wb + (size_t)(col0 + 64 + sr) * DIM + k0 + sc),
                                     LDS_AS(&Bs[64 + sr][sc]), 16, 0, 0);
    __syncthreads();
    bf16x8 af[4], bfr[4];
    #pragma unroll
    for (int mi = 0; mi < 4; mi++) af[mi] = *(const bf16x8*)(&As[wr + mi * 16 + lm][kq * 8]);
    #pragma unroll
    for (int ni = 0; ni < 4; ni++) bfr[ni] = *(const bf16x8*)(&Bs[wc + ni * 16 + lm][kq * 8]);
    #pragma unroll
    for (int mi = 0; mi < 4; mi++)
      #pragma unroll
      for (int ni = 0; ni < 4; ni++)
        acc[mi][ni] = __builtin_amdgcn_mfma_f32_16x16x32_bf16(af[mi], bfr[ni], acc[mi][ni], 0, 0, 0);
    __syncthreads();
  }

  const int rq = (lane >> 4) * 4;
  #pragma unroll
  for (int mi = 0; mi < 4; mi++){
    #pragma unroll
    for (int ni = 0; ni < 4; ni++){
      int col = col0 + wc + ni * 16 + lm;
      float bd = b_dec[col];
      #pragma unroll
      for (int r = 0; r < 4; r++){
        int row = row0 + wr + mi * 16 + rq + r;
        out[(size_t)row * DIM + col] = acc[mi][ni][r] + bd;
      }
    }
  }
}

// Chunked decode: block = (chunk = blockIdx&7, 16 tokens), thread = (token, 8 cols).
// out += sum_k act*Wdec_chunk[idx]; partial sse via block reduce + atomic.
__global__ __launch_bounds__(256) void decode_residual(
    const float* __restrict__ y,
    const float* __restrict__ la,
    const int*   __restrict__ li,
    const unsigned short* __restrict__ Wdc,  // [NCHUNK][NLAT][128] bf16
    const float* __restrict__ pe,
    const float* __restrict__ pes,
    float* __restrict__ out,
    float* __restrict__ sse){
  const int chunk = blockIdx.x & 7;
  const int tok0  = (blockIdx.x >> 3) * 16;
  const int t  = threadIdx.x;
  const int tl = t >> 4;       // token lane 0..15
  const int cl = t & 15;       // col lane 0..15 (8 cols each)
  __shared__ float s_act[16][KTOP];
  __shared__ int   s_idx[16][KTOP];
  __shared__ float s_red[4];
  #pragma unroll
  for (int i = 0; i < 4; i++){
    int e = t + i * 256;                 // 1024 entries: (tok = e>>6, k = e&63)
    int id = li[(tok0 + (e >> 6)) * KTOP + (e & 63)];
    s_idx[e >> 6][e & 63] = id;
    s_act[e >> 6][e & 63] = (la[(tok0 + (e >> 6)) * KTOP + (e & 63)] + pe[id]) * pes[id];
  }
  __syncthreads();
  const int n = tok0 + tl;
  float* op = out + (size_t)n * DIM + chunk * 128 + cl * 8;
  float4 o0 = ((const float4*)op)[0], o1 = ((const float4*)op)[1];
  float acc[8] = {o0.x, o0.y, o0.z, o0.w, o1.x, o1.y, o1.z, o1.w};
  const unsigned short* Wc = Wdc + (size_t)chunk * NLAT * 128 + cl * 8;
  #pragma unroll 8
  for (int k = 0; k < KTOP; k++){
    const float a = s_act[tl][k];
    const uint4 wv = *(const uint4*)(Wc + (size_t)s_idx[tl][k] * 128);
    acc[0] += a * bflo(wv.x); acc[1] += a * bfhi(wv.x);
    acc[2] += a * bflo(wv.y); acc[3] += a * bfhi(wv.y);
    acc[4] += a * bflo(wv.z); acc[5] += a * bfhi(wv.z);
    acc[6] += a * bflo(wv.w); acc[7] += a * bfhi(wv.w);
  }
  ((float4*)op)[0] = make_float4(acc[0], acc[1], acc[2], acc[3]);
  ((float4*)op)[1] = make_float4(acc[4], acc[5], acc[6], acc[7]);
  const float* yp = y + (size_t)n * DIM + chunk * 128 + cl * 8;
  float4 y0 = ((const float4*)yp)[0], y1 = ((const float4*)yp)[1];
  float e0 = y0.x - acc[0], e1 = y0.y - acc[1], e2 = y0.z - acc[2], e3 = y0.w - acc[3];
  float e4 = y1.x - acc[4], e5 = y1.y - acc[5], e6 = y1.z - acc[6], e7 = y1.w - acc[7];
  float s = e0*e0 + e1*e1 + e2*e2 + e3*e3 + e4*e4 + e5*e5 + e6*e6 + e7*e7;
  #pragma unroll
  for (int off = 32; off > 0; off >>= 1) s += __shfl_down(s, off, 64);
  if ((t & 63) == 0) s_red[t >> 6] = s;
  __syncthreads();
  if (t == 0) atomicAdd(sse, s_red[0] + s_red[1] + s_red[2] + s_red[3]);
}

__global__ __launch_bounds__(256) void ystats(
    const float* __restrict__ y, float* __restrict__ colsum, float* __restrict__ sumsq){
  const int t  = threadIdx.x;
  const int r0 = blockIdx.x * 32;
  float4 cs = {0.f, 0.f, 0.f, 0.f};
  float sq = 0.f;
  for (int r = 0; r < 32; r++){
    float4 v = ((const float4*)(y + (size_t)(r0 + r) * DIM))[t];
    cs.x += v.x; cs.y += v.y; cs.z += v.z; cs.w += v.w;
    sq += v.x*v.x + v.y*v.y + v.z*v.z + v.w*v.w;
  }
  atomicAdd(&colsum[t*4+0], cs.x);
  atomicAdd(&colsum[t*4+1], cs.y);
  atomicAdd(&colsum[t*4+2], cs.z);
  atomicAdd(&colsum[t*4+3], cs.w);
  #pragma unroll
  for (int off = 32; off > 0; off >>= 1) sq += __shfl_down(sq, off, 64);
  __shared__ float s_red[4];
  if ((t & 63) == 0) s_red[t >> 6] = sq;
  __syncthreads();
  if (t == 0) atomicAdd(sumsq, s_red[0] + s_red[1] + s_red[2] + s_red[3]);
}

__global__ __launch_bounds__(256) void fvu_kernel(
    const float* __restrict__ ws, float* __restrict__ fvu_out){
  const int t = threadIdx.x;
  float4 c = ((const float4*)(ws + 4))[t];
  float s = c.x*c.x + c.y*c.y + c.z*c.z + c.w*c.w;
  #pragma unroll
  for (int off = 32; off > 0; off >>= 1) s += __shfl_down(s, off, 64);
  __shared__ float s_red[4];
  if ((t & 63) == 0) s_red[t >> 6] = s;
  __syncthreads();
  if (t == 0){
    float ss = s_red[0] + s_red[1] + s_red[2] + s_red[3];
    float tv = ws[1] - ss / (float)N_TOK;
    fvu_out[0] = ws[0] / tv;
  }
}

extern "C" void kernel_launch(void* const* d_in, const int* in_sizes, int n_in,
                              void* d_out, int out_size, void* d_ws, size_t ws_size,
                              hipStream_t stream){
  const float* x   = (const float*)d_in[0];
  const float* y   = (const float*)d_in[1];
  const float* la  = (const float*)d_in[2];
  const int*   li  = (const int*)d_in[3];
  const float* Wd  = (const float*)d_in[4];
  const float* bd  = (const float*)d_in[5];
  const float* pe  = (const float*)d_in[6];
  const float* pes = (const float*)d_in[7];
  const float* Wsk = (const float*)d_in[8];
  float* out = (float*)d_out;

  float* accs = (float*)d_ws;  // [0]=sse [1]=sumsq [4..1028)=colsum
  unsigned short* xb  = (unsigned short*)((char*)d_ws + 8192);
  unsigned short* wb  = xb + (size_t)N_TOK * DIM;
  unsigned short* wdc = wb + (size_t)DIM * DIM;

  hipMemsetAsync(d_ws, 0, 8192, stream);
  cvt_bf16_kernel<<<N_TOK * DIM / 4 / 256, 256, 0, stream>>>(x,   xb, N_TOK * DIM / 4);
  cvt_bf16_kernel<<<DIM * DIM / 4 / 256,   256, 0, stream>>>(Wsk, wb, DIM * DIM / 4);
  cvt_wdec_chunked<<<NLAT, 256, 0, stream>>>(Wd, wdc);
  ystats<<<N_TOK / 32, 256, 0, stream>>>(y, accs + 4, accs + 1);
  skip_gemm<<<dim3(N_TOK / 128, DIM / 128), 256, 0, stream>>>(xb, wb, bd, out);
  decode_residual<<<(N_TOK / 16) * NCHUNK, 256, 0, stream>>>(y, la, li, wdc, pe, pes, out, accs);
  fvu_kernel<<<1, 256, 0, stream>>>(accs, out + (size_t)N_TOK * DIM);
}

// Round 4
// 227.939 us; speedup vs baseline: 1.5257x; 1.0635x over previous
//
#include <hip/hip_runtime.h>
#include <hip/hip_bf16.h>
#include <cstdint>

#define N_TOK 4096
#define KTOP  64
#define DIM   1024
#define NLAT  16384
#define NCHUNK 8      // 128 cols/chunk -> 4 MB bf16 per chunk == one XCD L2

typedef __bf16 bf16x8 __attribute__((ext_vector_type(8)));
typedef float  floatx4 __attribute__((ext_vector_type(4)));

#define GLOBAL_AS(p) ((const __attribute__((address_space(1))) void*)(p))
#define LDS_AS(p)    ((__attribute__((address_space(3))) void*)(p))

__device__ inline unsigned short f2bf(float f){
  unsigned int u = __float_as_uint(f);
  unsigned int r = (u + 0x7fffu + ((u >> 16) & 1u)) >> 16;  // RNE
  return (unsigned short)r;
}
__device__ inline float bflo(unsigned int u){ return __uint_as_float(u << 16); }
__device__ inline float bfhi(unsigned int u){ return __uint_as_float(u & 0xffff0000u); }

// Fused prep: [0,1024) x->bf16 | [1024,1280) Wskip->bf16 | [1280,3328) Wdec->chunked bf16
//             [3328,3456) ystats (colsum + sum y^2)
__global__ __launch_bounds__(256) void prep(
    const float* __restrict__ x, const float* __restrict__ Wsk,
    const float* __restrict__ Wd, const float* __restrict__ y,
    unsigned short* __restrict__ xb, unsigned short* __restrict__ wb,
    unsigned short* __restrict__ wdc,
    float* __restrict__ colsum, float* __restrict__ sumsq){
  const int b = blockIdx.x;
  const int t = threadIdx.x;
  if (b < 1024){
    int i0 = b * 1024 + t;
    #pragma unroll
    for (int i = 0; i < 4; i++){
      float4 v = ((const float4*)x)[i0 + i * 256];
      ushort4 o; o.x = f2bf(v.x); o.y = f2bf(v.y); o.z = f2bf(v.z); o.w = f2bf(v.w);
      ((ushort4*)xb)[i0 + i * 256] = o;
    }
  } else if (b < 1280){
    int i0 = (b - 1024) * 1024 + t;
    #pragma unroll
    for (int i = 0; i < 4; i++){
      float4 v = ((const float4*)Wsk)[i0 + i * 256];
      ushort4 o; o.x = f2bf(v.x); o.y = f2bf(v.y); o.z = f2bf(v.z); o.w = f2bf(v.w);
      ((ushort4*)wb)[i0 + i * 256] = o;
    }
  } else if (b < 3328){
    int lat0 = (b - 1280) * 8;
    const int chunk = t >> 5;
    const int off   = (t & 31) * 4;
    for (int r = 0; r < 8; r++){
      int lat = lat0 + r;
      float4 v = ((const float4*)(Wd + (size_t)lat * DIM))[t];
      ushort4 o; o.x = f2bf(v.x); o.y = f2bf(v.y); o.z = f2bf(v.z); o.w = f2bf(v.w);
      *(ushort4*)(wdc + ((size_t)chunk * NLAT + lat) * 128 + off) = o;
    }
  } else {
    const int r0 = (b - 3328) * 32;
    float4 cs = {0.f, 0.f, 0.f, 0.f};
    float sq = 0.f;
    for (int r = 0; r < 32; r++){
      float4 v = ((const float4*)(y + (size_t)(r0 + r) * DIM))[t];
      cs.x += v.x; cs.y += v.y; cs.z += v.z; cs.w += v.w;
      sq += v.x*v.x + v.y*v.y + v.z*v.z + v.w*v.w;
    }
    atomicAdd(&colsum[t*4+0], cs.x);
    atomicAdd(&colsum[t*4+1], cs.y);
    atomicAdd(&colsum[t*4+2], cs.z);
    atomicAdd(&colsum[t*4+3], cs.w);
    #pragma unroll
    for (int off = 32; off > 0; off >>= 1) sq += __shfl_down(sq, off, 64);
    __shared__ float s_red[4];
    if ((t & 63) == 0) s_red[t >> 6] = sq;
    __syncthreads();
    if (t == 0) atomicAdd(sumsq, s_red[0] + s_red[1] + s_red[2] + s_red[3]);
  }
}

// 128 rows x 64 cols tile -> 512 blocks (2 blocks/CU). m97-style staging.
__global__ __launch_bounds__(256) void skip_gemm(
    const unsigned short* __restrict__ xb,
    const unsigned short* __restrict__ wb,
    const float* __restrict__ b_dec,
    float* __restrict__ out){
  __shared__ unsigned short As[128][32];
  __shared__ unsigned short Bs[64][32];
  const int row0 = blockIdx.x * 128;
  const int col0 = blockIdx.y * 64;
  const int t    = threadIdx.x;
  const int lane = t & 63;
  const int w    = t >> 6;
  const int wr   = w * 32;
  const int lm   = lane & 15;
  const int kq   = lane >> 4;
  const int sr   = t >> 2;
  const int sc   = (t & 3) * 8;

  floatx4 acc[2][4] = {};

  for (int k0 = 0; k0 < DIM; k0 += 32){
    __builtin_amdgcn_global_load_lds(GLOBAL_AS(xb + (size_t)(row0 + sr) * DIM + k0 + sc),
                                     LDS_AS(&As[sr][sc]), 16, 0, 0);
    __builtin_amdgcn_global_load_lds(GLOBAL_AS(xb + (size_t)(row0 + 64 + sr) * DIM + k0 + sc),
                                     LDS_AS(&As[64 + sr][sc]), 16, 0, 0);
    __builtin_amdgcn_global_load_lds(GLOBAL_AS(wb + (size_t)(col0 + sr) * DIM + k0 + sc),
                                     LDS_AS(&Bs[sr][sc]), 16, 0, 0);
    __syncthreads();
    bf16x8 af[2], bfr[4];
    #pragma unroll
    for (int mi = 0; mi < 2; mi++) af[mi] = *(const bf16x8*)(&As[wr + mi * 16 + lm][kq * 8]);
    #pragma unroll
    for (int ni = 0; ni < 4; ni++) bfr[ni] = *(const bf16x8*)(&Bs[ni * 16 + lm][kq * 8]);
    #pragma unroll
    for (int mi = 0; mi < 2; mi++)
      #pragma unroll
      for (int ni = 0; ni < 4; ni++)
        acc[mi][ni] = __builtin_amdgcn_mfma_f32_16x16x32_bf16(af[mi], bfr[ni], acc[mi][ni], 0, 0, 0);
    __syncthreads();
  }

  const int rq = (lane >> 4) * 4;   // C/D: col=lane&15, row=(lane>>4)*4+reg
  #pragma unroll
  for (int mi = 0; mi < 2; mi++){
    #pragma unroll
    for (int ni = 0; ni < 4; ni++){
      int col = col0 + ni * 16 + lm;
      float bd = b_dec[col];
      #pragma unroll
      for (int r = 0; r < 4; r++){
        int row = row0 + wr + mi * 16 + rq + r;
        out[(size_t)row * DIM + col] = acc[mi][ni][r] + bd;
      }
    }
  }
}

// Chunked decode, conflict-free packed LDS, unroll 16.
__global__ __launch_bounds__(256) void decode_residual(
    const float* __restrict__ y,
    const float* __restrict__ la,
    const int*   __restrict__ li,
    const unsigned short* __restrict__ Wdc,  // [NCHUNK][NLAT][128] bf16
    const float* __restrict__ pe,
    const float* __restrict__ pes,
    float* __restrict__ out,
    float* __restrict__ sse){
  const int chunk = blockIdx.x & 7;
  const int tok0  = (blockIdx.x >> 3) * 16;
  const int t  = threadIdx.x;
  const int tl = t >> 4;       // token lane 0..15
  const int cl = t & 15;       // col lane (8 cols each)
  __shared__ uint2 s_ai[16][66];   // .x = act bits, .y = idx*256 (byte offset); stride 66 -> conflict-free
  __shared__ float s_red[4];
  #pragma unroll
  for (int i = 0; i < 4; i++){
    int e = t + i * 256;                 // (tok = e>>6, k = e&63)
    int tok = e >> 6, k = e & 63;
    int id = li[(tok0 + tok) * KTOP + k];
    float a = (la[(tok0 + tok) * KTOP + k] + pe[id]) * pes[id];
    s_ai[tok][k] = make_uint2(__float_as_uint(a), (unsigned)id * 256u);
  }
  __syncthreads();
  const int n = tok0 + tl;
  const char* Wbase = (const char*)Wdc + (size_t)chunk * NLAT * 256 + cl * 16;
  float* op = out + (size_t)n * DIM + chunk * 128 + cl * 8;
  const float* yp = y + (size_t)n * DIM + chunk * 128 + cl * 8;
  float4 o0 = ((const float4*)op)[0], o1 = ((const float4*)op)[1];
  float4 y0 = ((const float4*)yp)[0], y1 = ((const float4*)yp)[1];
  float acc[8] = {};
  #pragma unroll 16
  for (int k = 0; k < KTOP; k++){
    uint2 p = s_ai[tl][k];
    const float a = __uint_as_float(p.x);
    const uint4 wv = *(const uint4*)(Wbase + p.y);
    acc[0] += a * bflo(wv.x); acc[1] += a * bfhi(wv.x);
    acc[2] += a * bflo(wv.y); acc[3] += a * bfhi(wv.y);
    acc[4] += a * bflo(wv.z); acc[5] += a * bfhi(wv.z);
    acc[6] += a * bflo(wv.w); acc[7] += a * bfhi(wv.w);
  }
  acc[0] += o0.x; acc[1] += o0.y; acc[2] += o0.z; acc[3] += o0.w;
  acc[4] += o1.x; acc[5] += o1.y; acc[6] += o1.z; acc[7] += o1.w;
  ((float4*)op)[0] = make_float4(acc[0], acc[1], acc[2], acc[3]);
  ((float4*)op)[1] = make_float4(acc[4], acc[5], acc[6], acc[7]);
  float e0 = y0.x - acc[0], e1 = y0.y - acc[1], e2 = y0.z - acc[2], e3 = y0.w - acc[3];
  float e4 = y1.x - acc[4], e5 = y1.y - acc[5], e6 = y1.z - acc[6], e7 = y1.w - acc[7];
  float s = e0*e0 + e1*e1 + e2*e2 + e3*e3 + e4*e4 + e5*e5 + e6*e6 + e7*e7;
  #pragma unroll
  for (int off = 32; off > 0; off >>= 1) s += __shfl_down(s, off, 64);
  if ((t & 63) == 0) s_red[t >> 6] = s;
  __syncthreads();
  if (t == 0) atomicAdd(sse, s_red[0] + s_red[1] + s_red[2] + s_red[3]);
}

__global__ __launch_bounds__(256) void fvu_kernel(
    const float* __restrict__ ws, float* __restrict__ fvu_out){
  const int t = threadIdx.x;
  float4 c = ((const float4*)(ws + 4))[t];
  float s = c.x*c.x + c.y*c.y + c.z*c.z + c.w*c.w;
  #pragma unroll
  for (int off = 32; off > 0; off >>= 1) s += __shfl_down(s, off, 64);
  __shared__ float s_red[4];
  if ((t & 63) == 0) s_red[t >> 6] = s;
  __syncthreads();
  if (t == 0){
    float ss = s_red[0] + s_red[1] + s_red[2] + s_red[3];
    float tv = ws[1] - ss / (float)N_TOK;
    fvu_out[0] = ws[0] / tv;
  }
}

extern "C" void kernel_launch(void* const* d_in, const int* in_sizes, int n_in,
                              void* d_out, int out_size, void* d_ws, size_t ws_size,
                              hipStream_t stream){
  const float* x   = (const float*)d_in[0];
  const float* y   = (const float*)d_in[1];
  const float* la  = (const float*)d_in[2];
  const int*   li  = (const int*)d_in[3];
  const float* Wd  = (const float*)d_in[4];
  const float* bd  = (const float*)d_in[5];
  const float* pe  = (const float*)d_in[6];
  const float* pes = (const float*)d_in[7];
  const float* Wsk = (const float*)d_in[8];
  float* out = (float*)d_out;

  float* accs = (float*)d_ws;  // [0]=sse [1]=sumsq [4..1028)=colsum
  unsigned short* xb  = (unsigned short*)((char*)d_ws + 8192);
  unsigned short* wb  = xb + (size_t)N_TOK * DIM;
  unsigned short* wdc = wb + (size_t)DIM * DIM;

  hipMemsetAsync(d_ws, 0, 8192, stream);
  prep<<<3456, 256, 0, stream>>>(x, Wsk, Wd, y, xb, wb, wdc, accs + 4, accs + 1);
  skip_gemm<<<dim3(N_TOK / 128, DIM / 64), 256, 0, stream>>>(xb, wb, bd, out);
  decode_residual<<<(N_TOK / 16) * NCHUNK, 256, 0, stream>>>(y, la, li, wdc, pe, pes, out, accs);
  fvu_kernel<<<1, 256, 0, stream>>>(accs, out + (size_t)N_TOK * DIM);
}